// Round 11
// baseline (662.847 us; speedup 1.0000x reference)
//
#include <hip/hip_runtime.h>
#include <cstdint>

#define M_DIM 8192
#define K_DIM 4096
#define N_DIM 12288
#define KT 64  // K-tiles of BK=64 int8

using i32x4 = __attribute__((ext_vector_type(4))) int;

__device__ inline void gload_lds16(const void* g, void* l) {
    __builtin_amdgcn_global_load_lds(
        (const __attribute__((address_space(1))) void*)g,
        (__attribute__((address_space(3))) void*)l,
        16, 0, 0);
}

__device__ inline int pack4(int4 v) {
    return (v.x & 255) | ((v.y & 255) << 8) | ((v.z & 255) << 16) | (v.w << 24);
}

// ---- fused: per-row quant (blocks 0..M-1) + weight repack into per-wave-tiled B' ----
// B' granule layout (16 B units): idx = ((((bn*4+wn)*32 + j128)*4 + nf)*2 + ks)*64
//                                        + lk*16 + lr
// holding int8 of B[n= bn*256+wn*64+nf*16+lr][k = j128*128 + (ks*4+lk)*16 .. +16)
__global__ __launch_bounds__(256) void quant_pack(const float* __restrict__ x,
                                                  const int* __restrict__ w32,
                                                  int8_t* __restrict__ qa,
                                                  float* __restrict__ ascale,
                                                  int8_t* __restrict__ wb) {
    const int t = threadIdx.x;
    if (blockIdx.x < M_DIM) {
        const int row = blockIdx.x;
        const float4* xr = (const float4*)(x + (size_t)row * K_DIM);
        float4 v[4];
        float amax = 0.0f;
#pragma unroll
        for (int c = 0; c < 4; ++c) {
            v[c] = xr[t + 256 * c];
            amax = fmaxf(amax, fmaxf(fmaxf(fabsf(v[c].x), fabsf(v[c].y)),
                                     fmaxf(fabsf(v[c].z), fabsf(v[c].w))));
        }
#pragma unroll
        for (int off = 32; off > 0; off >>= 1)
            amax = fmaxf(amax, __shfl_xor(amax, off));
        __shared__ float smax[4];
        if ((t & 63) == 0) smax[t >> 6] = amax;
        __syncthreads();
        amax = fmaxf(fmaxf(smax[0], smax[1]), fmaxf(smax[2], smax[3]));
        const float sc = amax * (1.0f / 127.0f);
        const float inv = (amax > 0.0f) ? (127.0f / amax) : 0.0f;
        if (t == 0) ascale[row] = sc;

        int* q32 = (int*)(qa + (size_t)row * K_DIM);
#pragma unroll
        for (int c = 0; c < 4; ++c) {
            int q0 = (int)rintf(v[c].x * inv);
            int q1 = (int)rintf(v[c].y * inv);
            int q2 = (int)rintf(v[c].z * inv);
            int q3 = (int)rintf(v[c].w * inv);
            q0 = min(127, max(-128, q0));
            q1 = min(127, max(-128, q1));
            q2 = min(127, max(-128, q2));
            q3 = min(127, max(-128, q3));
            q32[t + 256 * c] = (q0 & 255) | ((q1 & 255) << 8) | ((q2 & 255) << 16) | (q3 << 24);
        }
    } else {
        const int pb = blockIdx.x - M_DIM;  // 0..2047
        const size_t total = (size_t)N_DIM * K_DIM / 16;  // 16B granules
        const size_t stride = (size_t)2048 * 256;
        for (size_t i = (size_t)pb * 256 + t; i < total; i += stride) {
            const uint32_t c = (uint32_t)i;
            const int lr = c & 15;
            const int lk = (c >> 4) & 3;
            const uint32_t q = c >> 6;
            const int ks = q & 1;
            const int nf = (q >> 1) & 3;
            const uint32_t r = q >> 3;
            const int j = r & 31;
            const uint32_t s2 = r >> 5;           // bn*4 + wn
            const int n = (int)(s2 >> 2) * 256 + (int)(s2 & 3) * 64 + nf * 16 + lr;
            const int k0 = j * 128 + (ks * 4 + lk) * 16;
            const int4* src = (const int4*)(w32 + (size_t)n * K_DIM + k0);
            const int4 v0 = src[0], v1 = src[1], v2 = src[2], v3 = src[3];
            i32x4 o;
            o[0] = pack4(v0); o[1] = pack4(v1); o[2] = pack4(v2); o[3] = pack4(v3);
            ((i32x4*)wb)[i] = o;
        }
    }
}

// ---- int8 GEMM: 256x256 block tile, BK=64, WAVE-PRIVATE A in LDS, B in regs,
// ---- ZERO barriers in the K-loop: per-wave counted vmcnt/lgkmcnt only.
__global__ __launch_bounds__(512, 2) void gemm_i8(const int8_t* __restrict__ qa,
                                                  const int8_t* __restrict__ wb,
                                                  const float* __restrict__ ascale,
                                                  const float* __restrict__ wscale,
                                                  const float* __restrict__ bias,
                                                  float* __restrict__ out) {
    __shared__ int8_t lds[8][2][8192];  // [wave][slot][128 rows x 64 B] = 128 KiB

    const int t = threadIdx.x;
    const int lane = t & 63;
    const int wave = t >> 6;       // 0..7
    const int wm = wave >> 2;      // 0..1 -> 128 rows of A
    const int wn = wave & 3;       // 0..3 -> 64 cols of C
    const int lrow = lane & 15;
    const int lk = lane >> 4;      // 0..3
    const int rslot = (lk ^ ((lrow >> 1) & 3)) << 4;  // r5 swizzle (measured 0 conflicts)

    // XCD-aware bijective swizzle: 1536 = 8 * 192
    const int flat = blockIdx.x;
    const int sw = (flat & 7) * 192 + (flat >> 3);
    const int bm = sw / 48;  // 0..31
    const int bn = sw % 48;  // 0..47

    // wave-private A staging: chunk c (0..7) covers local rows c*16+(lane>>2),
    // 16B sub-slot s = lane&3; linear LDS dest, global k-slot permuted by the
    // reader's involution: g = s ^ ((row>>1)&3) = (lane&3)^((lane>>3)&3).
    const int g = (lane & 3) ^ ((lane >> 3) & 3);
    const size_t abase = (size_t)(bm * 256 + wm * 128 + (lane >> 2)) * K_DIM +
                         (size_t)g * 16;

#define STAGE_A(sb, jt)                                                        \
    {                                                                          \
        _Pragma("unroll") for (int c = 0; c < 8; ++c)                          \
            gload_lds16(qa + abase + (size_t)(c * 16) * K_DIM +                \
                            (size_t)(jt) * 64,                                 \
                        &lds[wave][sb][c * 1024 + lane * 16]);                 \
    }
    // B': per-wave contiguous 1KB chunks, BK=128 granules split into 64-halves.
    const int8_t* wbase = wb + (size_t)(bn * 4 + wn) * 262144 + (size_t)lane * 16;
#define LOAD_B(dst, jt)                                                        \
    {                                                                          \
        _Pragma("unroll") for (int nf = 0; nf < 4; ++nf)                       \
            dst[nf] = *(const i32x4*)(wbase + (size_t)((jt) >> 1) * 8192 +     \
                                      (nf * 2 + ((jt)&1)) * 1024);             \
    }
#define SB0 __builtin_amdgcn_sched_barrier(0);
#define WAIT_LGKM(n) asm volatile("s_waitcnt lgkmcnt(" #n ")" ::: "memory");
#define WAIT_VM(n) asm volatile("s_waitcnt vmcnt(" #n ")" ::: "memory");

    i32x4 acc[8][4] = {};
    i32x4 a[8], b0[4], b1[4];

    // per-tile, fully per-wave (no s_barrier):
    //  vmcnt(4): A(J) landed (B(J) may fly) | ds_read 8 A frags
    //  | issue STAGE_A(J+1) + LOAD_B(J+1) | vmcnt(12): B(J) landed
    //  | lgkm(0): frags ready | 32 MFMA.
    // Ring-2 race: reads of slot J&1 are lgkm-drained in tile J (program order)
    // before tile J+1 issues the DMA overwriting slot (J+2)&1 = J&1? No --
    // STAGE_A(J+2) is issued in tile J+1, after tile J's lgkm(0). Race-free.
#define TILE(J, BC, BN)                                                        \
    {                                                                          \
        WAIT_VM(4);                                                            \
        SB0;                                                                   \
        _Pragma("unroll") for (int mf = 0; mf < 8; ++mf)                       \
            a[mf] = *(const i32x4*)&lds[wave][(J)&1][(mf * 16 + lrow) * 64 +   \
                                                    rslot];                    \
        if ((J) + 1 < KT) {                                                    \
            STAGE_A(((J) + 1) & 1, (J) + 1);                                   \
            LOAD_B(BN, (J) + 1);                                               \
            WAIT_VM(12);                                                       \
        } else {                                                               \
            WAIT_VM(0);                                                        \
        }                                                                      \
        SB0;                                                                   \
        WAIT_LGKM(0);                                                          \
        SB0;                                                                   \
        __builtin_amdgcn_s_setprio(1);                                         \
        _Pragma("unroll") for (int mf = 0; mf < 8; ++mf)                       \
            _Pragma("unroll") for (int nf = 0; nf < 4; ++nf)                   \
                acc[mf][nf] = __builtin_amdgcn_mfma_i32_16x16x64_i8(           \
                    a[mf], BC[nf], acc[mf][nf], 0, 0, 0);                      \
        __builtin_amdgcn_s_setprio(0);                                         \
        SB0;                                                                   \
    }

    // prologue: stage A(0), load B(0)
    STAGE_A(0, 0);
    LOAD_B(b0, 0);
    SB0;

    for (int j = 0; j < KT; j += 2) {
        TILE(j, b0, b1);
        TILE(j + 1, b1, b0);
    }

    // epilogue: C/D layout col = lane&15, row = (lane>>4)*4 + j
    const int r0 = bm * 256 + wm * 128;
    const int c0 = bn * 256 + wn * 64;
    float asc[8][4];
#pragma unroll
    for (int m = 0; m < 8; ++m)
#pragma unroll
        for (int jj = 0; jj < 4; ++jj)
            asc[m][jj] = ascale[r0 + m * 16 + lk * 4 + jj];
#pragma unroll
    for (int n = 0; n < 4; ++n) {
        const int col = c0 + n * 16 + lrow;
        const float wsc = wscale[col];
        const float bb = bias[col];
#pragma unroll
        for (int m = 0; m < 8; ++m) {
#pragma unroll
            for (int jj = 0; jj < 4; ++jj) {
                const int row = r0 + m * 16 + lk * 4 + jj;
                out[(size_t)row * N_DIM + col] = (float)acc[m][n][jj] * asc[m][jj] * wsc + bb;
            }
        }
    }
}

extern "C" void kernel_launch(void* const* d_in, const int* in_sizes, int n_in,
                              void* d_out, int out_size, void* d_ws, size_t ws_size,
                              hipStream_t stream) {
    const float* x = (const float*)d_in[0];
    const int* w32 = (const int*)d_in[1];  // int8 weights arrive as int32
    const float* wscale = (const float*)d_in[2];
    const float* bias = (const float*)d_in[3];
    float* out = (float*)d_out;

    int8_t* qa = (int8_t*)d_ws;                                     // M*K int8
    float* ascale = (float*)((char*)d_ws + (size_t)M_DIM * K_DIM);  // M f32
    int8_t* wb = (int8_t*)((char*)d_ws + (size_t)M_DIM * K_DIM +
                           (size_t)M_DIM * sizeof(float));          // N*K int8 (tiled B')

    quant_pack<<<M_DIM + 2048, 256, 0, stream>>>(x, w32, qa, ascale, wb);
    gemm_i8<<<1536, 512, 0, stream>>>(qa, wb, ascale, wscale, bias, out);
}

// Round 12
// 541.718 us; speedup vs baseline: 1.2236x; 1.2236x over previous
//
#include <hip/hip_runtime.h>
#include <cstdint>

#define M_DIM 8192
#define K_DIM 4096
#define N_DIM 12288
#define KT 64  // K-tiles of BK=64 int8 (64 B per row)

using i32x4 = __attribute__((ext_vector_type(4))) int;

__device__ inline void gload_lds16(const void* g, void* l) {
    __builtin_amdgcn_global_load_lds(
        (const __attribute__((address_space(1))) void*)g,
        (__attribute__((address_space(3))) void*)l,
        16, 0, 0);
}

// ---------------- fused: per-row quant (blocks 0..M-1) + weight repack ----------------
__global__ __launch_bounds__(256) void quant_pack(const float* __restrict__ x,
                                                  const int* __restrict__ w32,
                                                  int8_t* __restrict__ qa,
                                                  float* __restrict__ ascale,
                                                  int8_t* __restrict__ wq) {
    const int t = threadIdx.x;
    if (blockIdx.x < M_DIM) {
        const int row = blockIdx.x;
        const float4* xr = (const float4*)(x + (size_t)row * K_DIM);
        float4 v[4];
        float amax = 0.0f;
#pragma unroll
        for (int c = 0; c < 4; ++c) {
            v[c] = xr[t + 256 * c];
            amax = fmaxf(amax, fmaxf(fmaxf(fabsf(v[c].x), fabsf(v[c].y)),
                                     fmaxf(fabsf(v[c].z), fabsf(v[c].w))));
        }
#pragma unroll
        for (int off = 32; off > 0; off >>= 1)
            amax = fmaxf(amax, __shfl_xor(amax, off));
        __shared__ float smax[4];
        if ((t & 63) == 0) smax[t >> 6] = amax;
        __syncthreads();
        amax = fmaxf(fmaxf(smax[0], smax[1]), fmaxf(smax[2], smax[3]));
        const float sc = amax * (1.0f / 127.0f);
        const float inv = (amax > 0.0f) ? (127.0f / amax) : 0.0f;
        if (t == 0) ascale[row] = sc;

        int* q32 = (int*)(qa + (size_t)row * K_DIM);
#pragma unroll
        for (int c = 0; c < 4; ++c) {
            int q0 = (int)rintf(v[c].x * inv);
            int q1 = (int)rintf(v[c].y * inv);
            int q2 = (int)rintf(v[c].z * inv);
            int q3 = (int)rintf(v[c].w * inv);
            q0 = min(127, max(-128, q0));
            q1 = min(127, max(-128, q1));
            q2 = min(127, max(-128, q2));
            q3 = min(127, max(-128, q3));
            q32[t + 256 * c] = (q0 & 255) | ((q1 & 255) << 8) | ((q2 & 255) << 16) | (q3 << 24);
        }
    } else {
        const int pb = blockIdx.x - M_DIM;  // 0..2047
        const size_t total4 = (size_t)N_DIM * K_DIM / 4;
        const size_t stride = (size_t)2048 * 256;
        int* out32 = (int*)wq;
        for (size_t i = (size_t)pb * 256 + t; i < total4; i += stride) {
            const int4 v = ((const int4*)w32)[i];
            out32[i] = (v.x & 255) | ((v.y & 255) << 8) | ((v.z & 255) << 16) | (v.w << 24);
        }
    }
}

// ---- int8 GEMM: 256x256, BK=64, ring-4, branchless body, SGB-pinned
// ---- {8 MFMA, 3 ds_read} instruction interleave (reads prefetch next tile's frags)
__global__ __launch_bounds__(512, 2) void gemm_i8(const int8_t* __restrict__ qa,
                                                  const int8_t* __restrict__ wq,
                                                  const float* __restrict__ ascale,
                                                  const float* __restrict__ wscale,
                                                  const float* __restrict__ bias,
                                                  float* __restrict__ out) {
    __shared__ int8_t lds[4][2][16384];  // ring-4 K-tile slots x {A,B}, 128 KiB

    const int t = threadIdx.x;
    const int lane = t & 63;
    const int wave = t >> 6;       // 0..7
    const int wm = wave >> 2;      // 0..1 -> 128 rows of A
    const int wn = wave & 3;       // 0..3 -> 64 rows of B
    const int lrow = lane & 15;
    const int lk = lane >> 4;      // 0..3
    const int rslot = (lk ^ ((lrow >> 1) & 3)) << 4;  // measured 0 conflicts (r5/r9)

    // XCD-aware bijective swizzle: 1536 = 8 * 192
    const int flat = blockIdx.x;
    const int sw = (flat & 7) * 192 + (flat >> 3);
    const int bm = sw / 48;
    const int bn = sw % 48;

    // staging involution (linear LDS dest, permuted global k-slot) — r5-verified
    const int g = (t & 3) ^ ((t >> 3) & 3);
    const size_t aoff0 = (size_t)(bm * 256 + (t >> 2)) * K_DIM + (size_t)g * 16;
    const size_t aoff1 = aoff0 + (size_t)128 * K_DIM;
    const size_t boff0 = (size_t)(bn * 256 + (t >> 2)) * K_DIM + (size_t)g * 16;
    const size_t boff1 = boff0 + (size_t)128 * K_DIM;

#define STAGE_ALL(sb, jt)                                                      \
    {                                                                          \
        gload_lds16(qa + aoff0 + (size_t)(jt) * 64, &lds[sb][0][t * 16]);      \
        gload_lds16(qa + aoff1 + (size_t)(jt) * 64, &lds[sb][0][t * 16 + 8192]); \
        gload_lds16(wq + boff0 + (size_t)(jt) * 64, &lds[sb][1][t * 16]);      \
        gload_lds16(wq + boff1 + (size_t)(jt) * 64, &lds[sb][1][t * 16 + 8192]); \
    }

#define READS(S, NA, NB)                                                       \
    _Pragma("unroll") for (int nf = 0; nf < 4; ++nf)                           \
        NB[nf] = *(const i32x4*)&lds[S][1][(wn * 64 + nf * 16 + lrow) * 64 + rslot]; \
    _Pragma("unroll") for (int mf = 0; mf < 8; ++mf)                           \
        NA[mf] = *(const i32x4*)&lds[S][0][(wm * 128 + mf * 16 + lrow) * 64 + rslot];

#define MFMA32(CA, CB)                                                         \
    _Pragma("unroll") for (int mf = 0; mf < 8; ++mf)                           \
        _Pragma("unroll") for (int nf = 0; nf < 4; ++nf)                       \
            acc[mf][nf] = __builtin_amdgcn_mfma_i32_16x16x64_i8(               \
                CA[mf], CB[nf], acc[mf][nf], 0, 0, 0);

    // compile-time interleave: 4 x {8 MFMA, 3 ds_read} covers 32 MFMA + 12 reads
#define SGBPAT                                                                 \
    _Pragma("unroll") for (int c = 0; c < 4; ++c) {                            \
        __builtin_amdgcn_sched_group_barrier(0x008, 8, 0);                     \
        __builtin_amdgcn_sched_group_barrier(0x100, 3, 0);                     \
    }

#define SB0 __builtin_amdgcn_sched_barrier(0);
#define BAR __builtin_amdgcn_s_barrier();
#define WAIT_LGKM(n) asm volatile("s_waitcnt lgkmcnt(" #n ")" ::: "memory");
#define WAIT_VM(n) asm volatile("s_waitcnt vmcnt(" #n ")" ::: "memory");

    // straight-line tile: stage(J+3) | vmcnt(8): tile J+1 landed (own slice; BAR
    // globalizes) | BAR | region{ reads(J+1)->next set, 32 MFMA(cur set) } SGB-
    // interleaved | lgkm0 (next set ready; also closes slot-reuse window).
#define TILE_MAIN(J, CA, CB, NA, NB)                                           \
    {                                                                          \
        STAGE_ALL(((J) + 3) & 3, (J) + 3);                                     \
        WAIT_VM(8);                                                            \
        BAR;                                                                   \
        __builtin_amdgcn_s_setprio(1);                                         \
        READS(((J) + 1) & 3, NA, NB);                                          \
        MFMA32(CA, CB);                                                        \
        SGBPAT;                                                                \
        __builtin_amdgcn_s_setprio(0);                                         \
        WAIT_LGKM(0);                                                          \
        SB0;                                                                   \
    }
#define TILE_TAIL(VMN, S, CA, CB, NA, NB)                                      \
    {                                                                          \
        WAIT_VM(VMN);                                                          \
        BAR;                                                                   \
        __builtin_amdgcn_s_setprio(1);                                         \
        READS(S, NA, NB);                                                      \
        MFMA32(CA, CB);                                                        \
        SGBPAT;                                                                \
        __builtin_amdgcn_s_setprio(0);                                         \
        WAIT_LGKM(0);                                                          \
        SB0;                                                                   \
    }

    i32x4 acc[8][4] = {};
    i32x4 fa0[8], fb0[4], fa1[8], fb1[4];

    // prologue: stage tiles 0,1,2; tile 0 landed; prime set0 with tile-0 frags
    STAGE_ALL(0, 0);
    STAGE_ALL(1, 1);
    STAGE_ALL(2, 2);
    WAIT_VM(8);
    BAR;
    READS(0, fa0, fb0);
    WAIT_LGKM(0);
    SB0;

    // main loop: tiles 0..59 (stages reach tile 62), branchless body
    for (int jp = 0; jp < 30; ++jp) {
        const int j = jp * 2;
        TILE_MAIN(j, fa0, fb0, fa1, fb1);
        TILE_MAIN(j + 1, fa1, fb1, fa0, fb0);
    }
    // tails: tile 60 (stages 63), 61, 62, 63
    {
        STAGE_ALL(3, 63);
        TILE_TAIL(8, 61 & 3, fa0, fb0, fa1, fb1);  // tile 60; 61 landed
    }
    TILE_TAIL(4, 62 & 3, fa1, fb1, fa0, fb0);      // tile 61; 62 landed
    TILE_TAIL(0, 63 & 3, fa0, fb0, fa1, fb1);      // tile 62; 63 landed
    {
        __builtin_amdgcn_s_setprio(1);
        MFMA32(fa1, fb1);                           // tile 63, regs ready
        __builtin_amdgcn_s_setprio(0);
    }

    // epilogue: C/D layout col = lane&15, row = (lane>>4)*4 + j
    const int r0 = bm * 256 + wm * 128;
    const int c0 = bn * 256 + wn * 64;
    float asc[8][4];
#pragma unroll
    for (int m = 0; m < 8; ++m)
#pragma unroll
        for (int jj = 0; jj < 4; ++jj)
            asc[m][jj] = ascale[r0 + m * 16 + lk * 4 + jj];
#pragma unroll
    for (int n = 0; n < 4; ++n) {
        const int col = c0 + n * 16 + lrow;
        const float wsc = wscale[col];
        const float bb = bias[col];
#pragma unroll
        for (int m = 0; m < 8; ++m) {
#pragma unroll
            for (int jj = 0; jj < 4; ++jj) {
                const int row = r0 + m * 16 + lk * 4 + jj;
                out[(size_t)row * N_DIM + col] = (float)acc[m][n][jj] * asc[m][jj] * wsc + bb;
            }
        }
    }
}

extern "C" void kernel_launch(void* const* d_in, const int* in_sizes, int n_in,
                              void* d_out, int out_size, void* d_ws, size_t ws_size,
                              hipStream_t stream) {
    const float* x = (const float*)d_in[0];
    const int* w32 = (const int*)d_in[1];  // int8 weights arrive as int32
    const float* wscale = (const float*)d_in[2];
    const float* bias = (const float*)d_in[3];
    float* out = (float*)d_out;

    int8_t* qa = (int8_t*)d_ws;                                     // M*K int8
    float* ascale = (float*)((char*)d_ws + (size_t)M_DIM * K_DIM);  // M f32
    int8_t* wq = (int8_t*)((char*)d_ws + (size_t)M_DIM * K_DIM +
                           (size_t)M_DIM * sizeof(float));          // N*K int8

    quant_pack<<<M_DIM + 2048, 256, 0, stream>>>(x, w32, qa, ascale, wq);
    gemm_i8<<<1536, 512, 0, stream>>>(qa, wq, ascale, wscale, bias, out);
}